// Round 1
// baseline (106.706 us; speedup 1.0000x reference)
//
#include <hip/hip_runtime.h>

#define PP 7        // PH == PW == 7
#define KK 6        // K
#define SCALE_F 0.0625f
#define XMAX 40     // aligned x footprint cap (mult of 4; true max 37+3 align)
#define YMAX 40     // y footprint cap (true max 37)
#define CG  16      // channels per block
#define CH  8       // y rows per load chunk (loads in flight per lane)

__global__ __launch_bounds__(256, 4) void prroi_fwd(
    const float* __restrict__ feats, const float* __restrict__ rois,
    float* __restrict__ out, int C, int H, int W)
{
    __shared__ __align__(16) float sWy[PP][YMAX];       // dense y weights, rel y0
    __shared__ float sWx[PP][KK + 2];                   // sparse x weights
    __shared__ int   sGx[PP][KK + 2];                   // x indices rel x0a
    __shared__ __align__(16) float sT[CG][PP][XMAX];    // y-reduced intermediate

    const int n  = blockIdx.x;
    const int c0 = blockIdx.y * CG;
    const int t  = threadIdx.x;

    // ---- uniform scalars (every thread computes identically) ----
    const float* r = rois + (size_t)n * 5;
    const float rx1 = r[1] * SCALE_F, ry1 = r[2] * SCALE_F;
    const float rx2 = r[3] * SCALE_F, ry2 = r[4] * SCALE_F;
    const int   bn  = (int)r[0];
    const float bw  = fmaxf(rx2 - rx1, 0.0f) / (float)PP;
    const float bh  = fmaxf(ry2 - ry1, 0.0f) / (float)PP;
    const float win = bw * bh;
    const float inv = (win > 0.0f) ? (1.0f / fmaxf(win, 1e-12f)) : 0.0f;

    // x window (16B-aligned start; corners give min/max, matches ref clip)
    const int x0a  = (min(max((int)floorf(rx1), 0), W - 1)) & ~3;
    const int xmax = min(max((int)floorf(rx1 + bw * (float)(PP - 1)) + KK, 0), W - 1);
    const int G    = ((xmax - x0a + 1) + 3) >> 2;    // float4 slots per row, 1..10

    // y window (unique rows only)
    const int y0 = min(max((int)floorf(ry1), 0), H - 1);
    int ylast    = min(max((int)floorf(ry1 + bh * (float)(PP - 1)) + KK, 0), H - 1);
    if (ylast < y0) ylast = y0;
    const int ycnt = min(ylast - y0 + 1, YMAX);      // 1..37

    // ---- weight prologue (wave 0, lanes 0..13) ----
    if (t < 14) {
        const int  axis  = (t >= PP) ? 1 : 0;        // 0=y, 1=x
        const int  p     = axis ? t - PP : t;
        const float start = axis ? rx1 : ry1;
        const float binsz = axis ? bw  : bh;
        const int   size  = axis ? W   : H;
        const float ws = start + binsz * (float)p;
        const float we = ws + binsz;
        const float s  = floorf(ws);
        float w[KK + 1];
        #pragma unroll
        for (int k = 0; k <= KK; ++k) w[k] = 0.0f;
        #pragma unroll
        for (int k = 0; k < KK; ++k) {
            const float cell = s + (float)k;
            if (cell < we) {                         // strict, matches reference
                const float x0 = fmaxf(ws, cell);
                const float x1 = fminf(we, cell + 1.0f);
                const float a0 = x0 - cell, l0 = x1 - cell;
                w[k]     += l0 - 0.5f * l0 * l0 - a0 + 0.5f * a0 * a0;
                const float a1 = cell + 1.0f - x1, l1 = cell + 1.0f - x0;
                w[k + 1] += l1 - 0.5f * l1 * l1 - a1 + 0.5f * a1 * a1;
            }
        }
        const int si = (int)s;
        if (axis) {
            // x: keep sparse taps (consumed in pass 2)
            #pragma unroll
            for (int k = 0; k <= KK; ++k) {
                const int  idx   = si + k;
                const bool valid = (idx >= 0) && (idx < size);
                int rel = min(max(idx, 0), size - 1) - x0a;
                rel = min(max(rel, 0), XMAX - 1);    // invalid taps have w=0
                sWx[p][k] = valid ? w[k] : 0.0f;
                sGx[p][k] = rel;
            }
        } else {
            // y: scatter into dense row table (zero elsewhere)
            const float4 z = make_float4(0.f, 0.f, 0.f, 0.f);
            #pragma unroll
            for (int q = 0; q < YMAX / 4; ++q) *(float4*)&sWy[p][4 * q] = z;
            #pragma unroll
            for (int k = 0; k <= KK; ++k) {
                const int idx = si + k;
                if (idx >= 0 && idx < size) {
                    const int rr = idx - y0;
                    if (rr >= 0 && rr < YMAX) sWy[p][rr] = w[k];
                }
            }
        }
    }
    __syncthreads();

    // ---- pass 1: stream unique y rows once, dense-accumulate all 7 bins ----
    const int HW = H * W;
    const int cl = t / G;                            // lane owns (cl, g)
    if (cl < CG) {
        const int g    = t - cl * G;
        const int xcol = min(x0a + 4 * g, W - 4);    // W%4==0, never OOB
        const float* base = feats + (size_t)(bn * C + c0 + cl) * HW
                                  + (size_t)y0 * W + xcol;
        float4 acc[PP];
        #pragma unroll
        for (int i = 0; i < PP; ++i) acc[i] = make_float4(0.f, 0.f, 0.f, 0.f);

        const int nch = (ycnt + CH - 1) / CH;        // 1..5 chunks
        for (int ch = 0; ch < nch; ++ch) {
            const int yb = ch * CH;
            float4 buf[CH];                          // 8 loads in flight
            #pragma unroll
            for (int k = 0; k < CH; ++k) {
                const int yr = min(yb + k, ycnt - 1);   // pad rows: weight==0
                buf[k] = *(const float4*)(base + (size_t)yr * W);
            }
            #pragma unroll
            for (int i = 0; i < PP; ++i) {
                const float4 w0 = *(const float4*)&sWy[i][yb];       // broadcast
                const float4 w1 = *(const float4*)&sWy[i][yb + 4];
                const float wk[CH] = {w0.x, w0.y, w0.z, w0.w,
                                      w1.x, w1.y, w1.z, w1.w};
                float4 a = acc[i];
                #pragma unroll
                for (int k = 0; k < CH; ++k) {
                    a.x = fmaf(wk[k], buf[k].x, a.x);
                    a.y = fmaf(wk[k], buf[k].y, a.y);
                    a.z = fmaf(wk[k], buf[k].z, a.z);
                    a.w = fmaf(wk[k], buf[k].w, a.w);
                }
                acc[i] = a;
            }
        }
        #pragma unroll
        for (int i = 0; i < PP; ++i)
            *(float4*)&sT[cl][i][4 * g] = acc[i];
    }
    __syncthreads();

    // ---- pass 2: x-reduction from LDS ----
    for (int o = t; o < CG * PP * PP; o += 256) {
        const int j  = o % PP;
        const int i  = (o / PP) % PP;
        const int cc = o / (PP * PP);
        float acc = 0.0f;
        #pragma unroll
        for (int b = 0; b <= KK; ++b)
            acc = fmaf(sWx[j][b], sT[cc][i][sGx[j][b]], acc);
        out[((size_t)n * C + c0 + cc) * (PP * PP) + i * PP + j] = acc * inv;
    }
}

extern "C" void kernel_launch(void* const* d_in, const int* in_sizes, int n_in,
                              void* d_out, int out_size, void* d_ws, size_t ws_size,
                              hipStream_t stream) {
    const float* feats = (const float*)d_in[0];
    const float* rois  = (const float*)d_in[1];
    float* out = (float*)d_out;

    const int C = 64, H = 200, W = 304;
    const int N = in_sizes[1] / 5;

    dim3 grid(N, C / CG), block(256);
    hipLaunchKernelGGL(prroi_fwd, grid, block, 0, stream,
                       feats, rois, out, C, H, W);
}

// Round 2
// 105.273 us; speedup vs baseline: 1.0136x; 1.0136x over previous
//
#include <hip/hip_runtime.h>

#define PP 7        // PH == PW == 7
#define KK 6        // K
#define SCALE_F 0.0625f
#define XMAX 40     // aligned x footprint cap (mult of 4; true max 37+3 align)
#define YW   44     // dense y-weight table width (max rel row 40, +4 pad, mult 4)
#define CG   16     // channels per block
#define GMIN 6      // pad x footprint to >=6 float4 slots (lane-util floor)

template<int NN>
__device__ __forceinline__ void y_chunk(const float* base, int W, int r0yb,
                                        int ycnt, const float (*sWyp)[YW],
                                        float4 acc[PP])
{
    float4 buf[NN];                                  // NN loads in flight
    #pragma unroll
    for (int k = 0; k < NN; ++k) {
        const int yr = min(r0yb + k, ycnt - 1);      // pad rows: weight==0
        buf[k] = *(const float4*)(base + (size_t)yr * W);
    }
    #pragma unroll
    for (int i = 0; i < PP; ++i) {
        const float4 w0 = *(const float4*)&sWyp[i][r0yb];        // broadcast
        float wk[NN];
        wk[0] = w0.x; wk[1] = w0.y; wk[2] = w0.z; wk[3] = w0.w;
        if (NN == 8) {
            const float4 w1 = *(const float4*)&sWyp[i][r0yb + 4];
            wk[4] = w1.x; wk[5] = w1.y; wk[6] = w1.z; wk[7] = w1.w;
        }
        float4 a = acc[i];
        #pragma unroll
        for (int k = 0; k < NN; ++k) {
            a.x = fmaf(wk[k], buf[k].x, a.x);
            a.y = fmaf(wk[k], buf[k].y, a.y);
            a.z = fmaf(wk[k], buf[k].z, a.z);
            a.w = fmaf(wk[k], buf[k].w, a.w);
        }
        acc[i] = a;
    }
}

__global__ __launch_bounds__(256, 4) void prroi_fwd(
    const float* __restrict__ feats, const float* __restrict__ rois,
    float* __restrict__ out, int C, int H, int W)
{
    __shared__ __align__(16) float sWy[PP][YW];      // dense y weights, rel y0
    __shared__ float sWx[PP][KK + 2];                // sparse x weights
    __shared__ int   sGx[PP][KK + 2];                // x indices rel x0a
    __shared__ __align__(16) float sT [CG][PP][XMAX];  // slice-0 partials
    __shared__ __align__(16) float sT2[CG][PP][XMAX];  // slice-1 partials

    const int n  = blockIdx.x;
    const int c0 = blockIdx.y * CG;
    const int t  = threadIdx.x;

    // ---- uniform scalars (every thread computes identically; SGPR math) ----
    const float* r = rois + (size_t)n * 5;
    const float rx1 = r[1] * SCALE_F, ry1 = r[2] * SCALE_F;
    const float rx2 = r[3] * SCALE_F, ry2 = r[4] * SCALE_F;
    const int   bn  = (int)r[0];
    const float bw  = fmaxf(rx2 - rx1, 0.0f) / (float)PP;
    const float bh  = fmaxf(ry2 - ry1, 0.0f) / (float)PP;
    const float win = bw * bh;
    const float inv = (win > 0.0f) ? (1.0f / fmaxf(win, 1e-12f)) : 0.0f;

    // x window (16B-aligned start; corners give min/max, matches ref clip)
    const int x0a  = (min(max((int)floorf(rx1), 0), W - 1)) & ~3;
    const int xmax = min(max((int)floorf(rx1 + bw * (float)(PP - 1)) + KK, 0), W - 1);
    const int G    = ((xmax - x0a + 1) + 3) >> 2;    // true float4 slots, 1..10
    const int Ge   = max(G, GMIN);                   // padded slots (extra cols w=0)
    const int P    = CG * Ge;                        // (cl,g) tasks: 96..160
    const int S    = (P <= 128) ? 2 : 1;             // y slices

    // y window (unique rows only)
    const int y0 = min(max((int)floorf(ry1), 0), H - 1);
    int ylast    = min(max((int)floorf(ry1 + bh * (float)(PP - 1)) + KK, 0), H - 1);
    if (ylast < y0) ylast = y0;
    const int ycnt = min(ylast - y0 + 1, XMAX);      // 1..38

    // slice-0 row count: 4-aligned; S=2 -> 4*ceil(ycnt/8), S=1 -> 4*ceil(ycnt/4)
    const int half = (S == 2) ? (((ycnt + 7) >> 3) << 2)
                              : (((ycnt + 3) >> 2) << 2);

    // ---- weight prologue (wave 0, lanes 0..13) ----
    if (t < 14) {
        const int  axis  = (t >= PP) ? 1 : 0;        // 0=y, 1=x
        const int  p     = axis ? t - PP : t;
        const float start = axis ? rx1 : ry1;
        const float binsz = axis ? bw  : bh;
        const int   size  = axis ? W   : H;
        const float ws = start + binsz * (float)p;
        const float we = ws + binsz;
        const float s  = floorf(ws);
        float w[KK + 1];
        #pragma unroll
        for (int k = 0; k <= KK; ++k) w[k] = 0.0f;
        #pragma unroll
        for (int k = 0; k < KK; ++k) {
            const float cell = s + (float)k;
            if (cell < we) {                         // strict, matches reference
                const float x0 = fmaxf(ws, cell);
                const float x1 = fminf(we, cell + 1.0f);
                const float a0 = x0 - cell, l0 = x1 - cell;
                w[k]     += l0 - 0.5f * l0 * l0 - a0 + 0.5f * a0 * a0;
                const float a1 = cell + 1.0f - x1, l1 = cell + 1.0f - x0;
                w[k + 1] += l1 - 0.5f * l1 * l1 - a1 + 0.5f * a1 * a1;
            }
        }
        const int si = (int)s;
        if (axis) {
            // x: sparse taps for pass 2; invalid taps -> weight 0, index 0
            #pragma unroll
            for (int k = 0; k <= KK; ++k) {
                const int  idx   = si + k;
                const bool valid = (idx >= 0) && (idx < size);
                sWx[p][k] = valid ? w[k] : 0.0f;
                sGx[p][k] = valid ? (idx - x0a) : 0;   // valid => in [0, 4G)
            }
        } else {
            // y: scatter into dense row table (zero elsewhere)
            const float4 z = make_float4(0.f, 0.f, 0.f, 0.f);
            #pragma unroll
            for (int q = 0; q < YW / 4; ++q) *(float4*)&sWy[p][4 * q] = z;
            #pragma unroll
            for (int k = 0; k <= KK; ++k) {
                const int idx = si + k;
                if (idx >= 0 && idx < size) {
                    const int rr = idx - y0;
                    if (rr >= 0 && rr < YW) sWy[p][rr] = w[k];
                }
            }
        }
    }
    __syncthreads();

    // ---- pass 1: stream unique y rows, sliced across all lanes ----
    const int HW = H * W;
    if (t < S * P) {
        const int sl = (t >= P) ? 1 : 0;             // y slice
        const int id = t - sl * P;
        const int cl = id / Ge;
        const int g  = id - cl * Ge;
        const int xcol = min(x0a + 4 * g, W - 4);    // W%4==0, never OOB
        const int r0   = sl * half;                  // first rel row of slice
        // slice rows (mult of 4): slice0 = half; slice1 = pad4(ycnt-half)
        const int rows = sl ? min((max(ycnt - half, 0) + 3) & ~3, half) : half;

        const float* base = feats + (size_t)(bn * C + c0 + cl) * HW
                                  + (size_t)y0 * W + xcol;
        float4 acc[PP];
        #pragma unroll
        for (int i = 0; i < PP; ++i) acc[i] = make_float4(0.f, 0.f, 0.f, 0.f);

        for (int yb = 0; yb < rows; yb += 8) {
            if (rows - yb >= 8) y_chunk<8>(base, W, r0 + yb, ycnt, sWy, acc);
            else                y_chunk<4>(base, W, r0 + yb, ycnt, sWy, acc);
        }

        float (*dst)[PP][XMAX] = sl ? sT2 : sT;      // slice1 lanes always write
        #pragma unroll                               // (zeros if rows==0)
        for (int i = 0; i < PP; ++i)
            *(float4*)&dst[cl][i][4 * g] = acc[i];
    }
    __syncthreads();

    // ---- pass 2: x-reduction, merging slice partials ----
    for (int o = t; o < CG * PP * PP; o += 256) {
        const int j  = o % PP;
        const int i  = (o / PP) % PP;
        const int cc = o / (PP * PP);
        float acc = 0.0f;
        if (S == 2) {
            #pragma unroll
            for (int b = 0; b <= KK; ++b) {
                const int x = sGx[j][b];
                acc = fmaf(sWx[j][b], sT[cc][i][x] + sT2[cc][i][x], acc);
            }
        } else {
            #pragma unroll
            for (int b = 0; b <= KK; ++b)
                acc = fmaf(sWx[j][b], sT[cc][i][sGx[j][b]], acc);
        }
        out[((size_t)n * C + c0 + cc) * (PP * PP) + i * PP + j] = acc * inv;
    }
}

extern "C" void kernel_launch(void* const* d_in, const int* in_sizes, int n_in,
                              void* d_out, int out_size, void* d_ws, size_t ws_size,
                              hipStream_t stream) {
    const float* feats = (const float*)d_in[0];
    const float* rois  = (const float*)d_in[1];
    float* out = (float*)d_out;

    const int C = 64, H = 200, W = 304;
    const int N = in_sizes[1] / 5;

    dim3 grid(N, C / CG), block(256);
    hipLaunchKernelGGL(prroi_fwd, grid, block, 0, stream,
                       feats, rois, out, C, H, W);
}

// Round 3
// 104.190 us; speedup vs baseline: 1.0241x; 1.0104x over previous
//
#include <hip/hip_runtime.h>

#define PP 7        // PH == PW == 7
#define KK 6        // K
#define SCALE_F 0.0625f
#define XMAX 40     // aligned x footprint cap (mult of 4; true max 37+3 align)
#define CG  8       // channels per block

// (256, 8): 8 waves/SIMD -> 8 blocks/CU (32 waves), caps VGPR at 64.
// Round-0 inner-loop lane state (~40 VGPR) fits; doubles latency hiding
// vs a 65..128-VGPR allocation (waves/CU halve at 64/128/256 on gfx950).
__global__ __launch_bounds__(256, 8) void prroi_fwd(
    const float* __restrict__ feats, const float* __restrict__ rois,
    float* __restrict__ out, int C, int H, int W)
{
    __shared__ float sW[4][14][8];                      // per-wave weights (y:0-6, x:7-13)
    __shared__ int   sG[4][14][8];                      // per-wave indices (x stored rel)
    __shared__ __align__(16) float sT[CG][PP][XMAX];    // y-reduced intermediate

    const int n    = blockIdx.x;
    const int c0   = blockIdx.y * CG;
    const int t    = threadIdx.x;
    const int wave = t >> 6, lane = t & 63;

    // ---- wave-uniform scalars (every lane computes; SGPR math) ----
    const float* r = rois + (size_t)n * 5;
    const float rx1 = r[1] * SCALE_F, ry1 = r[2] * SCALE_F;
    const float rx2 = r[3] * SCALE_F, ry2 = r[4] * SCALE_F;
    const int   bn  = (int)r[0];
    const float bw  = fmaxf(rx2 - rx1, 0.0f) / (float)PP;
    const float bh  = fmaxf(ry2 - ry1, 0.0f) / (float)PP;
    const float win = bw * bh;
    const float inv = (win > 0.0f) ? (1.0f / fmaxf(win, 1e-12f)) : 0.0f;
    // x window: floor(ws(p)) is monotone in p; corners give min/max (matches ref clip)
    const int x0a  = (min(max((int)floorf(rx1), 0), W - 1)) & ~3;          // 16B aligned
    const int xmax = min(max((int)floorf(rx1 + bw * (float)(PP - 1)) + KK, 0), W - 1);
    const int G    = ((xmax - x0a + 1) + 3) >> 2;   // float4 slots per row, 1..10
    const int R    = 64 / G;                         // rows per wave-load

    // ---- per-wave weight prologue (lanes 0..13, all waves in parallel) ----
    if (lane < 14) {
        const int  axis  = (lane >= PP) ? 1 : 0;     // 0=y, 1=x
        const int  p     = axis ? lane - PP : lane;
        const float start = axis ? rx1 : ry1;
        const float binsz = axis ? bw  : bh;
        const int   size  = axis ? W   : H;
        const float ws = start + binsz * (float)p;
        const float we = ws + binsz;
        const float s  = floorf(ws);
        float w[KK + 1];
        #pragma unroll
        for (int k = 0; k <= KK; ++k) w[k] = 0.0f;
        #pragma unroll
        for (int k = 0; k < KK; ++k) {
            const float cell = s + (float)k;
            if (cell < we) {                         // strict, matches reference
                const float x0 = fmaxf(ws, cell);
                const float x1 = fminf(we, cell + 1.0f);
                const float a0 = x0 - cell, l0 = x1 - cell;
                w[k]     += l0 - 0.5f * l0 * l0 - a0 + 0.5f * a0 * a0;
                const float a1 = cell + 1.0f - x1, l1 = cell + 1.0f - x0;
                w[k + 1] += l1 - 0.5f * l1 * l1 - a1 + 0.5f * a1 * a1;
            }
        }
        const int si = (int)s;
        #pragma unroll
        for (int k = 0; k <= KK; ++k) {
            const int  idx   = si + k;
            const bool valid = (idx >= 0) && (idx < size);
            int ic = min(max(idx, 0), size - 1);
            if (axis) ic -= x0a;                     // x: store relative to window
            sW[wave][lane][k] = valid ? w[k] : 0.0f;
            sG[wave][lane][k] = ic;
        }
    }
    __syncthreads();

    // ---- pass 1: y-reduction, fixed-i lanes, weights hoisted to registers ----
    const int HW  = H * W;
    const int rr  = lane / G;
    const int g   = lane - rr * G;
    const int xcol = min(x0a + 4 * g, W - 4);        // aligned tail clamp (W%4==0)
    if (rr < R) {
        const int q  = wave * R + rr;                // q < 4R, 4R >= 24 covers i 0..6
        const int i  = q % 7;
        const int Pi = (4 * R + 6 - i) / 7;          // cl stride for this residue
        int cl = q / 7;
        if (cl < CG) {
            float wy[KK + 1]; int ro[KK + 1];
            #pragma unroll
            for (int a = 0; a <= KK; ++a) {
                wy[a] = sW[wave][i][a];
                ro[a] = sG[wave][i][a] * W;
            }
            // 32-bit in-loop addressing: one pointer bump per cl iteration
            const float* base = feats + (size_t)(bn * C + c0 + cl) * HW + xcol;
            const int step = Pi * HW;
            for (; cl < CG; cl += Pi, base += step) {
                float4 acc = make_float4(0.f, 0.f, 0.f, 0.f);
                #pragma unroll
                for (int a = 0; a <= KK; ++a) {
                    const float4 v = *(const float4*)(base + ro[a]);
                    acc.x = fmaf(wy[a], v.x, acc.x);
                    acc.y = fmaf(wy[a], v.y, acc.y);
                    acc.z = fmaf(wy[a], v.z, acc.z);
                    acc.w = fmaf(wy[a], v.w, acc.w);
                }
                ((float4*)&sT[cl][i][0])[g] = acc;
            }
        }
    }
    __syncthreads();

    // ---- pass 2: x-reduction from LDS ----
    for (int o = t; o < CG * PP * PP; o += 256) {
        const int j  = o % PP;
        const int i  = (o / PP) % PP;
        const int cl = o / (PP * PP);
        float acc = 0.0f;
        #pragma unroll
        for (int b = 0; b <= KK; ++b)
            acc = fmaf(sW[wave][PP + j][b], sT[cl][i][sG[wave][PP + j][b]], acc);
        out[((size_t)n * C + c0 + cl) * (PP * PP) + i * PP + j] = acc * inv;
    }
}

extern "C" void kernel_launch(void* const* d_in, const int* in_sizes, int n_in,
                              void* d_out, int out_size, void* d_ws, size_t ws_size,
                              hipStream_t stream) {
    const float* feats = (const float*)d_in[0];
    const float* rois  = (const float*)d_in[1];
    float* out = (float*)d_out;

    const int C = 64, H = 200, W = 304;
    const int N = in_sizes[1] / 5;

    dim3 grid(N, C / CG), block(256);
    hipLaunchKernelGGL(prroi_fwd, grid, block, 0, stream,
                       feats, rois, out, C, H, W);
}